// Round 2
// baseline (181.976 us; speedup 1.0000x reference)
//
#include <hip/hip_runtime.h>
#include <math.h>

// Problem constants (fixed by setup_inputs):
//   B=4, N=2048, D=512, H=4, A=64, V=64, L=6400
//   qkvb (bf16, L x 768): [0:256)=v, [256:512)=q, [512:768)=k
//   A2   (bf16, L x 1024): [0:256)=u, [256:768)=x, [768:1024)=y(unused now, LN fused into gemm2)
#define NSEQ 2048
#define PIT 72    // LDS pitch (bf16 elems): 144B rows -> 4-bank row shift, b128 reads 2-way (free)
#define YP 264    // Ys pitch: 528B rows -> 4-bank shift; b128 A-frag reads ~2-way

typedef __attribute__((ext_vector_type(8))) short short8;   // 8 bf16 = 4 VGPR
typedef __attribute__((ext_vector_type(4))) short short4v;  // 4 bf16 = 2 VGPR
typedef __attribute__((ext_vector_type(4))) float f32x4;    // MFMA acc

// fast silu: z * rcp(1 + exp(-z)) — 1-ulp rcp instead of correctly-rounded divide
__device__ __forceinline__ float silu_f(float z) {
    return z * __builtin_amdgcn_rcpf(1.f + __expf(-z));
}

__device__ __forceinline__ unsigned short f2bf(float f) {
    unsigned int u = __float_as_uint(f);
    u += 0x7fffu + ((u >> 16) & 1u);   // RNE (finite inputs only)
    return (unsigned short)(u >> 16);
}

__device__ __forceinline__ unsigned short f2bf_fast(float f) {
    return (unsigned short)((__float_as_uint(f) + 0x8000u) >> 16);
}

// exact for power-of-2 scale
__device__ __forceinline__ short8 scale8_pow2(short8 v, float s) {
    short8 r;
    #pragma unroll
    for (int i = 0; i < 8; i++) {
        float f = __uint_as_float(((unsigned int)(unsigned short)v[i]) << 16) * s;
        r[i] = (short)(unsigned short)(__float_as_uint(f) >> 16);
    }
    return r;
}

// ---------------- prep: weight transposes + input LN in ONE launch ----------------
// blocks [0,512):    W1 (512x1024 -> 1024x512 bf16)
// blocks [512,1024): W2 (1024x512 -> 512x1024 bf16)
// blocks [1024, 1024+L/4): ln512, 4 rows/block (wave per row, no barrier)
__global__ void __launch_bounds__(256) prep_kernel(
    const float* __restrict__ W1, unsigned short* __restrict__ W1t,
    const float* __restrict__ W2, unsigned short* __restrict__ W2t,
    const float* __restrict__ x, const float* __restrict__ inw,
    const float* __restrict__ inb,
    unsigned short* __restrict__ nxb, unsigned short* __restrict__ A2)
{
    __shared__ float t[32][33];
    int id = blockIdx.x;
    int tid = threadIdx.x;
    if (id < 1024) {
        const float* W; unsigned short* Wt; int R, C, bx, by;
        if (id < 512) { W = W1; Wt = W1t; R = 512;  C = 1024; bx = id & 31; by = id >> 5; }
        else { int i2 = id - 512; W = W2; Wt = W2t; R = 1024; C = 512; bx = i2 & 15; by = i2 >> 4; }
        int tr = tid >> 5, tc = tid & 31;
        int r0 = by * 32, c0 = bx * 32;
        #pragma unroll
        for (int p = 0; p < 4; p++)
            t[tr + p * 8][tc] = W[(size_t)(r0 + tr + p * 8) * C + c0 + tc];
        __syncthreads();
        #pragma unroll
        for (int p = 0; p < 4; p++)
            Wt[(size_t)(c0 + tr + p * 8) * R + r0 + tc] = f2bf(t[tc][tr + p * 8]);
        return;
    }
    // ---- ln512 path ----
    int lane = tid & 63, wv = tid >> 6;
    int row = (id - 1024) * 4 + wv;
    int c = lane * 8;
    const float* xr = x + (size_t)row * 512 + c;
    float4 v0 = *(const float4*)xr;
    float4 v1 = *(const float4*)(xr + 4);
    float s  = v0.x + v0.y + v0.z + v0.w + v1.x + v1.y + v1.z + v1.w;
    float sq = v0.x * v0.x + v0.y * v0.y + v0.z * v0.z + v0.w * v0.w
             + v1.x * v1.x + v1.y * v1.y + v1.z * v1.z + v1.w * v1.w;
    #pragma unroll
    for (int o = 32; o > 0; o >>= 1) { s += __shfl_xor(s, o); sq += __shfl_xor(sq, o); }
    float mu = s * (1.f / 512.f);
    float var = sq * (1.f / 512.f) - mu * mu;
    float rs = rsqrtf(var + 1e-6f);
    float4 w0 = *(const float4*)(inw + c), w1 = *(const float4*)(inw + c + 4);
    float4 b0 = *(const float4*)(inb + c), b1 = *(const float4*)(inb + c + 4);
    ushort4 hn0, hn1, hx0, hx1;
    hn0.x = f2bf((v0.x - mu) * rs * w0.x + b0.x);
    hn0.y = f2bf((v0.y - mu) * rs * w0.y + b0.y);
    hn0.z = f2bf((v0.z - mu) * rs * w0.z + b0.z);
    hn0.w = f2bf((v0.w - mu) * rs * w0.w + b0.w);
    hn1.x = f2bf((v1.x - mu) * rs * w1.x + b1.x);
    hn1.y = f2bf((v1.y - mu) * rs * w1.y + b1.y);
    hn1.z = f2bf((v1.z - mu) * rs * w1.z + b1.z);
    hn1.w = f2bf((v1.w - mu) * rs * w1.w + b1.w);
    hx0.x = f2bf(v0.x); hx0.y = f2bf(v0.y); hx0.z = f2bf(v0.z); hx0.w = f2bf(v0.w);
    hx1.x = f2bf(v1.x); hx1.y = f2bf(v1.y); hx1.z = f2bf(v1.z); hx1.w = f2bf(v1.w);
    unsigned short* nr = nxb + (size_t)row * 512 + c;
    *(ushort4*)nr = hn0; *(ushort4*)(nr + 4) = hn1;
    unsigned short* ar = A2 + (size_t)row * 1024 + 256 + c;
    *(ushort4*)ar = hx0; *(ushort4*)(ar + 4) = hx1;
}

// ---------------- GEMM1 (MFMA bf16, 64x128 tile, BK=64, reg prefetch) ----------------
// A: nxb (L x 512), B: W1t (1024 x 512, N-major). silu(A@B^T + bias) -> A2 u / qkvb.
// 800 blocks (3/CU); 16 MFMA per barrier-pair; next K-tile loads fly during compute.
__global__ void __launch_bounds__(256) gemm1_mfma(
    const unsigned short* __restrict__ Ab, const unsigned short* __restrict__ Bt,
    const float* __restrict__ bias,
    unsigned short* __restrict__ A2, unsigned short* __restrict__ qkvb)
{
    constexpr int K = 512, KIT = K / 64;
    __shared__ unsigned short As[64 * PIT];
    __shared__ unsigned short Bs[128 * PIT];
    int tid = threadIdx.x, lane = tid & 63, w = tid >> 6;
    int wr = w >> 1, wc = w & 1;
    int nn = lane & 15, qd = lane >> 4;
    int bm = blockIdx.y * 64, bn = blockIdx.x * 128;
    int arow = tid >> 2, ac0 = (tid & 3) * 16;      // A: 64 rows x 64 cols, 32B/thread
    int brow = tid >> 1, bc0 = (tid & 1) * 32;      // B: 128 rows x 64 cols, 64B/thread
    const unsigned short* Ag = Ab + (size_t)(bm + arow) * K + ac0;
    const unsigned short* Bg = Bt + (size_t)(bn + brow) * K + bc0;

    short8 pa0 = *(const short8*)Ag, pa1 = *(const short8*)(Ag + 8);
    short8 pb0 = *(const short8*)Bg, pb1 = *(const short8*)(Bg + 8);
    short8 pb2 = *(const short8*)(Bg + 16), pb3 = *(const short8*)(Bg + 24);

    f32x4 acc[2][4];
    #pragma unroll
    for (int i = 0; i < 2; i++)
        #pragma unroll
        for (int j = 0; j < 4; j++) acc[i][j] = (f32x4){0.f, 0.f, 0.f, 0.f};

    for (int it = 0; it < KIT; ++it) {
        __syncthreads();
        *(short8*)&As[arow * PIT + ac0]     = pa0;
        *(short8*)&As[arow * PIT + ac0 + 8] = pa1;
        *(short8*)&Bs[brow * PIT + bc0]      = pb0;
        *(short8*)&Bs[brow * PIT + bc0 + 8]  = pb1;
        *(short8*)&Bs[brow * PIT + bc0 + 16] = pb2;
        *(short8*)&Bs[brow * PIT + bc0 + 24] = pb3;
        __syncthreads();
        if (it + 1 < KIT) {
            int k0 = (it + 1) * 64;
            pa0 = *(const short8*)(Ag + k0); pa1 = *(const short8*)(Ag + k0 + 8);
            pb0 = *(const short8*)(Bg + k0); pb1 = *(const short8*)(Bg + k0 + 8);
            pb2 = *(const short8*)(Bg + k0 + 16); pb3 = *(const short8*)(Bg + k0 + 24);
        }
        #pragma unroll
        for (int kk = 0; kk < 2; kk++) {
            short8 af[2], bf[4];
            #pragma unroll
            for (int i = 0; i < 2; i++)
                af[i] = *(const short8*)&As[(wr * 32 + i * 16 + nn) * PIT + kk * 32 + qd * 8];
            #pragma unroll
            for (int j = 0; j < 4; j++)
                bf[j] = *(const short8*)&Bs[(wc * 64 + j * 16 + nn) * PIT + kk * 32 + qd * 8];
            #pragma unroll
            for (int i = 0; i < 2; i++)
                #pragma unroll
                for (int j = 0; j < 4; j++)
                    acc[i][j] = __builtin_amdgcn_mfma_f32_16x16x32_bf16(af[i], bf[j], acc[i][j], 0, 0, 0);
        }
    }
    bool isU = (bn < 256);   // block-uniform: 128-col tiles align with the u/vqk boundary
    #pragma unroll
    for (int j = 0; j < 4; j++) {
        int col = bn + wc * 64 + j * 16 + nn;
        float bb = bias[col];
        #pragma unroll
        for (int i = 0; i < 2; i++) {
            int rbase = bm + wr * 32 + i * 16 + qd * 4;
            #pragma unroll
            for (int r = 0; r < 4; r++) {
                unsigned short hh = f2bf(silu_f(acc[i][j][r] + bb));
                if (isU) A2[(size_t)(rbase + r) * 1024 + col] = hh;
                else     qkvb[(size_t)(rbase + r) * 768 + col - 256] = hh;
            }
        }
    }
}

// ---------------- GEMM2 + fused output-LN ----------------
// Phase 0: y = LN(attn[bm:bm+64, 0:256)) -> Ys (LDS, bf16).  K-loop: out = x + [u|x|y] @ Wo,
// where A-cols [0,768) stream from A2 global and cols [768,1024) stream from Ys.
__global__ void __launch_bounds__(256) gemm2_ln_mfma(
    const unsigned short* __restrict__ Ab, const unsigned short* __restrict__ Bt,
    const float* __restrict__ attn, const float* __restrict__ ow,
    const float* __restrict__ ob,
    const float* __restrict__ x, float* __restrict__ out)
{
    constexpr int K = 1024, KIT = K / 64;
    __shared__ unsigned short As[64 * PIT];
    __shared__ unsigned short Bs[128 * PIT];
    __shared__ __align__(16) unsigned short Ys[64 * YP];
    int tid = threadIdx.x, lane = tid & 63, w = tid >> 6;
    int wr = w >> 1, wc = w & 1;
    int nn = lane & 15, qd = lane >> 4;
    int bm = blockIdx.y * 64, bn = blockIdx.x * 128;
    int arow = tid >> 2, ac0 = (tid & 3) * 16;
    int brow = tid >> 1, bc0 = (tid & 1) * 32;
    const unsigned short* Ag = Ab + (size_t)(bm + arow) * K + ac0;
    const unsigned short* Bg = Bt + (size_t)(bn + brow) * K + bc0;

    // issue first-tile global prefetch early: HBM latency hides under the LN phase
    short8 pa0 = *(const short8*)Ag, pa1 = *(const short8*)(Ag + 8);
    short8 pb0 = *(const short8*)Bg, pb1 = *(const short8*)(Bg + 8);
    short8 pb2 = *(const short8*)(Bg + 16), pb3 = *(const short8*)(Bg + 24);

    // ---- phase 0: output LN for this block's 64 rows (thread = row x 64-col quarter) ----
    {
        int rrow = tid >> 2, qq = tid & 3;
        const float* ar = attn + (size_t)(bm + rrow) * 256 + qq * 64;
        float vx[64];
        float s = 0.f, sq = 0.f;
        #pragma unroll
        for (int i = 0; i < 16; i++) {
            float4 v4 = *(const float4*)(ar + i * 4);
            vx[4 * i] = v4.x; vx[4 * i + 1] = v4.y; vx[4 * i + 2] = v4.z; vx[4 * i + 3] = v4.w;
            s += v4.x + v4.y + v4.z + v4.w;
            sq += v4.x * v4.x + v4.y * v4.y + v4.z * v4.z + v4.w * v4.w;
        }
        s += __shfl_xor(s, 1); sq += __shfl_xor(sq, 1);
        s += __shfl_xor(s, 2); sq += __shfl_xor(sq, 2);
        float mu = s * (1.f / 256.f);
        float var = sq * (1.f / 256.f) - mu * mu;
        float rs = rsqrtf(var + 1e-6f);
        unsigned short* yr = &Ys[rrow * YP + qq * 64];
        #pragma unroll
        for (int i = 0; i < 16; i++) {
            float4 w4 = *(const float4*)(ow + qq * 64 + i * 4);
            float4 b4 = *(const float4*)(ob + qq * 64 + i * 4);
            ushort4 h;
            h.x = f2bf((vx[4 * i]     - mu) * rs * w4.x + b4.x);
            h.y = f2bf((vx[4 * i + 1] - mu) * rs * w4.y + b4.y);
            h.z = f2bf((vx[4 * i + 2] - mu) * rs * w4.z + b4.z);
            h.w = f2bf((vx[4 * i + 3] - mu) * rs * w4.w + b4.w);
            *(ushort4*)(yr + i * 4) = h;
        }
    }
    __syncthreads();   // Ys visible to all waves before K-loop reads it

    f32x4 acc[2][4];
    #pragma unroll
    for (int i = 0; i < 2; i++)
        #pragma unroll
        for (int j = 0; j < 4; j++) acc[i][j] = (f32x4){0.f, 0.f, 0.f, 0.f};

    for (int it = 0; it < KIT; ++it) {
        __syncthreads();
        *(short8*)&As[arow * PIT + ac0]     = pa0;
        *(short8*)&As[arow * PIT + ac0 + 8] = pa1;
        *(short8*)&Bs[brow * PIT + bc0]      = pb0;
        *(short8*)&Bs[brow * PIT + bc0 + 8]  = pb1;
        *(short8*)&Bs[brow * PIT + bc0 + 16] = pb2;
        *(short8*)&Bs[brow * PIT + bc0 + 24] = pb3;
        __syncthreads();
        if (it + 1 < KIT) {
            int k0 = (it + 1) * 64;
            if (k0 < 768) {
                pa0 = *(const short8*)(Ag + k0); pa1 = *(const short8*)(Ag + k0 + 8);
            } else {
                const unsigned short* ys = &Ys[arow * YP + (k0 - 768) + ac0];
                pa0 = *(const short8*)ys; pa1 = *(const short8*)(ys + 8);
            }
            pb0 = *(const short8*)(Bg + k0); pb1 = *(const short8*)(Bg + k0 + 8);
            pb2 = *(const short8*)(Bg + k0 + 16); pb3 = *(const short8*)(Bg + k0 + 24);
        }
        #pragma unroll
        for (int kk = 0; kk < 2; kk++) {
            short8 af[2], bf[4];
            #pragma unroll
            for (int i = 0; i < 2; i++)
                af[i] = *(const short8*)&As[(wr * 32 + i * 16 + nn) * PIT + kk * 32 + qd * 8];
            #pragma unroll
            for (int j = 0; j < 4; j++)
                bf[j] = *(const short8*)&Bs[(wc * 64 + j * 16 + nn) * PIT + kk * 32 + qd * 8];
            #pragma unroll
            for (int i = 0; i < 2; i++)
                #pragma unroll
                for (int j = 0; j < 4; j++)
                    acc[i][j] = __builtin_amdgcn_mfma_f32_16x16x32_bf16(af[i], bf[j], acc[i][j], 0, 0, 0);
        }
    }
    #pragma unroll
    for (int j = 0; j < 4; j++) {
        int col = bn + wc * 64 + j * 16 + nn;
        #pragma unroll
        for (int i = 0; i < 2; i++) {
            int rbase = bm + wr * 32 + i * 16 + qd * 4;
            #pragma unroll
            for (int r = 0; r < 4; r++) {
                size_t idx = (size_t)(rbase + r) * 512 + col;
                out[idx] = x[idx] + acc[i][j][r];
            }
        }
    }
}

// ---------------- Attention (MFMA bf16, wave-private m-split, no atomics) ----------------
// 1D grid, bh-major id decode: id mod 8 is constant per (b,h) pair -> all tiles of a
// given bh land on the same XCD (2 bh per XCD; K/V working set <= ~832 KB fits 4 MB L2).
// Deep tiles (xt=0 -> n0=1984) get the smallest ids -> dispatched first.
__global__ void __launch_bounds__(256, 2) attn_mfma_kernel(
    const unsigned short* __restrict__ qkvb,
    const int* __restrict__ offsets,
    const int* __restrict__ lengths,
    const int* __restrict__ num_targets,
    float* __restrict__ attn)
{
    int id = blockIdx.x;
    int bh = id & 15;
    int xt = id >> 4;
    int b = bh >> 2, h = bh & 3;
    int len = lengths[b];
    int n0 = (31 - xt) * 64;                // deep tiles dispatched first
    if (n0 >= len) return;
    int m_hi = min(n0 + 63, len - 1);
    int off = offsets[b];
    int max_id = len - num_targets[b];
    int tid = threadIdx.x, lane = tid & 63, w = tid >> 6;
    int nn = lane & 15, qd = lane >> 4;

    __shared__ __align__(16) char smem[69632];
    unsigned short* Vt = (unsigned short*)(smem + w * 9216);  // wave-private 64x72 bf16
    float* Os = (float*)smem;                                 // overlay: 4 x (64x68) f32

    // Q B-frags for all 4 n-groups, alpha=0.125 folded (exact pow2)
    short8 qf[4][2];
    #pragma unroll
    for (int g = 0; g < 4; g++) {
        int row = min(n0 + g * 16 + nn, len - 1);
        const unsigned short* base = qkvb + (size_t)(off + row) * 768 + 256 + h * 64;
        qf[g][0] = scale8_pow2(*(const short8*)(base + qd * 8), 0.125f);
        qf[g][1] = scale8_pow2(*(const short8*)(base + 32 + qd * 8), 0.125f);
    }

    f32x4 o_acc[4][4];   // [t: v-subtile][g: n-group], O^T C-layout
    #pragma unroll
    for (int t = 0; t < 4; t++)
        #pragma unroll
        for (int g = 0; g < 4; g++) o_acc[t][g] = (f32x4){0.f, 0.f, 0.f, 0.f};

    int fast_lim = min(n0, max_id);
    int r0 = (lane & 15) * 4, d0 = (lane >> 4) * 16;   // V staging: 4 rows x 16 dims

    short8 kf[4][2], kn[4][2], vf[4][2];
    int m_first = w * 64;
    if (m_first <= m_hi) {
        #pragma unroll
        for (int s = 0; s < 4; s++) {
            int row = min(m_first + s * 16 + nn, len - 1);
            const unsigned short* kb = qkvb + (size_t)(off + row) * 768 + 512 + h * 64 + qd * 8;
            kf[s][0] = *(const short8*)kb;
            kf[s][1] = *(const short8*)(kb + 32);
        }
        #pragma unroll
        for (int j = 0; j < 4; j++) {
            int row = min(m_first + r0 + j, len - 1);
            const unsigned short* vb = qkvb + (size_t)(off + row) * 768 + h * 64 + d0;
            vf[j][0] = *(const short8*)vb;
            vf[j][1] = *(const short8*)(vb + 8);
        }
    }

    for (int m0 = m_first; m0 <= m_hi; m0 += 256) {
        #pragma unroll
        for (int dd = 0; dd < 16; dd++) {
            int hh = dd >> 3, e = dd & 7;
            short4v pk;
            pk[0] = vf[0][hh][e]; pk[1] = vf[1][hh][e];
            pk[2] = vf[2][hh][e]; pk[3] = vf[3][hh][e];
            *(short4v*)&Vt[(d0 + dd) * PIT + r0] = pk;
        }
        int mnext = m0 + 256;
        if (mnext <= m_hi) {
            #pragma unroll
            for (int j = 0; j < 4; j++) {
                int row = min(mnext + r0 + j, len - 1);
                const unsigned short* vb = qkvb + (size_t)(off + row) * 768 + h * 64 + d0;
                vf[j][0] = *(const short8*)vb;
                vf[j][1] = *(const short8*)(vb + 8);
            }
            #pragma unroll
            for (int s = 0; s < 4; s++) {
                int row = min(mnext + s * 16 + nn, len - 1);
                const unsigned short* kb = qkvb + (size_t)(off + row) * 768 + 512 + h * 64 + qd * 8;
                kn[s][0] = *(const short8*)kb;
                kn[s][1] = *(const short8*)(kb + 32);
            }
        }
        bool fastp = (m0 + 63 < fast_lim);
        #pragma unroll
        for (int s = 0; s < 4; s++) {
            f32x4 st[4];
            __builtin_amdgcn_s_setprio(1);
            #pragma unroll
            for (int g = 0; g < 4; g++) {
                st[g] = (f32x4){0.f, 0.f, 0.f, 0.f};
                st[g] = __builtin_amdgcn_mfma_f32_16x16x32_bf16(kf[s][0], qf[g][0], st[g], 0, 0, 0);
                st[g] = __builtin_amdgcn_mfma_f32_16x16x32_bf16(kf[s][1], qf[g][1], st[g], 0, 0, 0);
            }
            __builtin_amdgcn_s_setprio(0);
            short4v bop[4];
            if (fastp) {
                #pragma unroll
                for (int g = 0; g < 4; g++)
                    #pragma unroll
                    for (int r = 0; r < 4; r++)
                        bop[g][r] = (short)f2bf_fast(silu_f(st[g][r]));
            } else {
                #pragma unroll
                for (int g = 0; g < 4; g++) {
                    int nc_ = n0 + g * 16 + nn;
                    int id_ = min(nc_, max_id);
                    #pragma unroll
                    for (int r = 0; r < 4; r++) {
                        int mcol = m0 + s * 16 + qd * 4 + r;
                        bool ok = (mcol < id_) || (mcol == nc_);
                        bop[g][r] = (short)f2bf_fast(ok ? silu_f(st[g][r]) : 0.f);
                    }
                }
            }
            __builtin_amdgcn_s_setprio(1);
            #pragma unroll
            for (int t = 0; t < 4; t++) {
                short4v aop = *(const short4v*)&Vt[(t * 16 + nn) * PIT + s * 16 + qd * 4];
                #pragma unroll
                for (int g = 0; g < 4; g++)
                    o_acc[t][g] = __builtin_amdgcn_mfma_f32_16x16x16bf16_1k(aop, bop[g], o_acc[t][g], 0, 0, 0);
            }
            __builtin_amdgcn_s_setprio(0);
        }
        if (mnext <= m_hi) {
            #pragma unroll
            for (int s = 0; s < 4; s++) { kf[s][0] = kn[s][0]; kf[s][1] = kn[s][1]; }
        }
    }

    __syncthreads();
    const float invN = 1.f / (float)NSEQ;
    float* Ow = Os + w * 4352;
    #pragma unroll
    for (int t = 0; t < 4; t++)
        #pragma unroll
        for (int g = 0; g < 4; g++) {
            f32x4 v = o_acc[t][g] * invN;
            *(f32x4*)&Ow[(g * 16 + nn) * 68 + t * 16 + qd * 4] = v;
        }
    __syncthreads();
    int rr = tid >> 2, cs = (tid & 3) * 16;
    if (n0 + rr < len) {
        float* dst = attn + (size_t)(off + n0 + rr) * 256 + h * 64 + cs;
        #pragma unroll
        for (int q4 = 0; q4 < 4; q4++) {
            f32x4 v = (f32x4){0.f, 0.f, 0.f, 0.f};
            #pragma unroll
            for (int w2 = 0; w2 < 4; w2++)
                v += *(const f32x4*)&Os[w2 * 4352 + rr * 68 + cs + q4 * 4];
            *(f32x4*)(dst + q4 * 4) = v;
        }
    }
}

extern "C" void kernel_launch(void* const* d_in, const int* in_sizes, int n_in,
                              void* d_out, int out_size, void* d_ws, size_t ws_size,
                              hipStream_t stream)
{
    const float* x          = (const float*)d_in[0];
    const int*   x_lengths  = (const int*)d_in[1];
    const int*   x_offsets  = (const int*)d_in[2];
    // d_in[3] = max_seq_len (2048, hardcoded as NSEQ)
    const int*   num_targets = (const int*)d_in[4];
    const float* uvqk_w     = (const float*)d_in[5];
    const float* uvqk_b     = (const float*)d_in[6];
    const float* in_w       = (const float*)d_in[7];
    const float* in_b       = (const float*)d_in[8];
    const float* out_w      = (const float*)d_in[9];
    const float* out_b      = (const float*)d_in[10];
    const float* Wo         = (const float*)d_in[11];
    float* out = (float*)d_out;

    int L = in_sizes[0] / 512;   // 6400

    char* ws = (char*)d_ws;
    size_t o = 0;
    float* attn = (float*)(ws + o);          o += (size_t)L * 256 * 4;   // fp32 attn
    unsigned short* nxb  = (unsigned short*)(ws + o); o += (size_t)L * 512 * 2;
    unsigned short* A2   = (unsigned short*)(ws + o); o += (size_t)L * 1024 * 2;
    unsigned short* qkvb = (unsigned short*)(ws + o); o += (size_t)L * 768 * 2;
    unsigned short* W1t  = (unsigned short*)(ws + o); o += (size_t)1024 * 512 * 2;
    unsigned short* W2t  = (unsigned short*)(ws + o); o += (size_t)512 * 1024 * 2;

    // 0) weight transposes + input LN, single launch
    prep_kernel<<<dim3(1024 + L / 4), 256, 0, stream>>>(
        uvqk_w, W1t, Wo, W2t, x, in_w, in_b, nxb, A2);

    // 1) uvqk = silu(nx @ W1 + b): u -> A2[:,0:256), v/q/k -> qkvb  (800 blocks)
    dim3 g1(1024 / 128, L / 64);
    gemm1_mfma<<<g1, 256, 0, stream>>>(nxb, W1t, uvqk_b, A2, qkvb);

    // 2) attention (1D grid, bh-major XCD-locality swizzle, deep-first)
    attn_mfma_kernel<<<dim3(512), 256, 0, stream>>>(qkvb, x_offsets, x_lengths, num_targets, attn);

    // 3) out = x + [u|x|LN(attn)] @ Wo  (400 blocks, output-LN fused)
    dim3 g3(512 / 128, L / 64);
    gemm2_ln_mfma<<<g3, 256, 0, stream>>>(A2, W2t, attn, out_w, out_b, x, out);
}

// Round 3
// 166.222 us; speedup vs baseline: 1.0948x; 1.0948x over previous
//
#include <hip/hip_runtime.h>
#include <math.h>

// Problem constants (fixed by setup_inputs):
//   B=4, N=2048, D=512, H=4, A=64, V=64, L=6400
//   qkvb (bf16, L x 768): [0:256)=v, [256:512)=q, [512:768)=k
//   A2   (bf16, L x 1024): [0:256)=u, [256:768)=x, [768:1024)=y
#define NSEQ 2048
#define PIT 72    // LDS pitch (bf16 elems): 144B rows -> 4-bank row shift, b128 reads 2-way (free)

typedef __attribute__((ext_vector_type(8))) short short8;   // 8 bf16 = 4 VGPR
typedef __attribute__((ext_vector_type(4))) short short4v;  // 4 bf16 = 2 VGPR
typedef __attribute__((ext_vector_type(4))) float f32x4;    // MFMA acc

// fast silu: z * rcp(1 + exp(-z)) — 1-ulp rcp instead of correctly-rounded divide
__device__ __forceinline__ float silu_f(float z) {
    return z * __builtin_amdgcn_rcpf(1.f + __expf(-z));
}

__device__ __forceinline__ unsigned short f2bf(float f) {
    unsigned int u = __float_as_uint(f);
    u += 0x7fffu + ((u >> 16) & 1u);   // RNE (finite inputs only)
    return (unsigned short)(u >> 16);
}

__device__ __forceinline__ unsigned short f2bf_fast(float f) {
    return (unsigned short)((__float_as_uint(f) + 0x8000u) >> 16);
}

// exact for power-of-2 scale
__device__ __forceinline__ short8 scale8_pow2(short8 v, float s) {
    short8 r;
    #pragma unroll
    for (int i = 0; i < 8; i++) {
        float f = __uint_as_float(((unsigned int)(unsigned short)v[i]) << 16) * s;
        r[i] = (short)(unsigned short)(__float_as_uint(f) >> 16);
    }
    return r;
}

// ---------------- prep: weight transposes + input LN in ONE launch ----------------
// blocks [0,512):    W1 (512x1024 -> 1024x512 bf16)
// blocks [512,1024): W2 (1024x512 -> 512x1024 bf16)
// blocks [1024, 1024+L/4): ln512, 4 rows/block (wave per row, no barrier)
__global__ void __launch_bounds__(256) prep_kernel(
    const float* __restrict__ W1, unsigned short* __restrict__ W1t,
    const float* __restrict__ W2, unsigned short* __restrict__ W2t,
    const float* __restrict__ x, const float* __restrict__ inw,
    const float* __restrict__ inb,
    unsigned short* __restrict__ nxb, unsigned short* __restrict__ A2)
{
    __shared__ float t[32][33];
    int id = blockIdx.x;
    int tid = threadIdx.x;
    if (id < 1024) {
        const float* W; unsigned short* Wt; int R, C, bx, by;
        if (id < 512) { W = W1; Wt = W1t; R = 512;  C = 1024; bx = id & 31; by = id >> 5; }
        else { int i2 = id - 512; W = W2; Wt = W2t; R = 1024; C = 512; bx = i2 & 15; by = i2 >> 4; }
        int tr = tid >> 5, tc = tid & 31;
        int r0 = by * 32, c0 = bx * 32;
        #pragma unroll
        for (int p = 0; p < 4; p++)
            t[tr + p * 8][tc] = W[(size_t)(r0 + tr + p * 8) * C + c0 + tc];
        __syncthreads();
        #pragma unroll
        for (int p = 0; p < 4; p++)
            Wt[(size_t)(c0 + tr + p * 8) * R + r0 + tc] = f2bf(t[tc][tr + p * 8]);
        return;
    }
    // ---- ln512 path ----
    int lane = tid & 63, wv = tid >> 6;
    int row = (id - 1024) * 4 + wv;
    int c = lane * 8;
    const float* xr = x + (size_t)row * 512 + c;
    float4 v0 = *(const float4*)xr;
    float4 v1 = *(const float4*)(xr + 4);
    float s  = v0.x + v0.y + v0.z + v0.w + v1.x + v1.y + v1.z + v1.w;
    float sq = v0.x * v0.x + v0.y * v0.y + v0.z * v0.z + v0.w * v0.w
             + v1.x * v1.x + v1.y * v1.y + v1.z * v1.z + v1.w * v1.w;
    #pragma unroll
    for (int o = 32; o > 0; o >>= 1) { s += __shfl_xor(s, o); sq += __shfl_xor(sq, o); }
    float mu = s * (1.f / 512.f);
    float var = sq * (1.f / 512.f) - mu * mu;
    float rs = rsqrtf(var + 1e-6f);
    float4 w0 = *(const float4*)(inw + c), w1 = *(const float4*)(inw + c + 4);
    float4 b0 = *(const float4*)(inb + c), b1 = *(const float4*)(inb + c + 4);
    ushort4 hn0, hn1, hx0, hx1;
    hn0.x = f2bf((v0.x - mu) * rs * w0.x + b0.x);
    hn0.y = f2bf((v0.y - mu) * rs * w0.y + b0.y);
    hn0.z = f2bf((v0.z - mu) * rs * w0.z + b0.z);
    hn0.w = f2bf((v0.w - mu) * rs * w0.w + b0.w);
    hn1.x = f2bf((v1.x - mu) * rs * w1.x + b1.x);
    hn1.y = f2bf((v1.y - mu) * rs * w1.y + b1.y);
    hn1.z = f2bf((v1.z - mu) * rs * w1.z + b1.z);
    hn1.w = f2bf((v1.w - mu) * rs * w1.w + b1.w);
    hx0.x = f2bf(v0.x); hx0.y = f2bf(v0.y); hx0.z = f2bf(v0.z); hx0.w = f2bf(v0.w);
    hx1.x = f2bf(v1.x); hx1.y = f2bf(v1.y); hx1.z = f2bf(v1.z); hx1.w = f2bf(v1.w);
    unsigned short* nr = nxb + (size_t)row * 512 + c;
    *(ushort4*)nr = hn0; *(ushort4*)(nr + 4) = hn1;
    unsigned short* ar = A2 + (size_t)row * 1024 + 256 + c;
    *(ushort4*)ar = hx0; *(ushort4*)(ar + 4) = hx1;
}

// ---------------- LN over 256 (output): one wave per row, no LDS/barrier ----------------
__global__ void __launch_bounds__(256) ln256_kernel(
    const float* __restrict__ a, const float* __restrict__ w,
    const float* __restrict__ b, unsigned short* __restrict__ A2)
{
    int tid = threadIdx.x, lane = tid & 63, wv = tid >> 6;
    int row = blockIdx.x * 4 + wv;
    int c = lane * 4;
    float4 v = *(const float4*)(a + (size_t)row * 256 + c);
    float s  = v.x + v.y + v.z + v.w;
    float sq = v.x * v.x + v.y * v.y + v.z * v.z + v.w * v.w;
    #pragma unroll
    for (int o = 32; o > 0; o >>= 1) { s += __shfl_xor(s, o); sq += __shfl_xor(sq, o); }
    float mu = s * (1.f / 256.f);
    float var = sq * (1.f / 256.f) - mu * mu;
    float rs = rsqrtf(var + 1e-6f);
    float4 w4 = *(const float4*)(w + c);
    float4 b4 = *(const float4*)(b + c);
    ushort4 h;
    h.x = f2bf((v.x - mu) * rs * w4.x + b4.x);
    h.y = f2bf((v.y - mu) * rs * w4.y + b4.y);
    h.z = f2bf((v.z - mu) * rs * w4.z + b4.z);
    h.w = f2bf((v.w - mu) * rs * w4.w + b4.w);
    *(ushort4*)(A2 + (size_t)row * 1024 + 768 + c) = h;
}

// ---------------- GEMM1 (MFMA bf16, 64x128 tile, BK=64, reg prefetch) ----------------
// A: nxb (L x 512), B: W1t (1024 x 512, N-major). silu(A@B^T + bias) -> A2 u / qkvb.
// 1D grid, XCD-chunked: physical id p -> logical l=(p&7)*100+(p>>3), so each XCD gets a
// contiguous chunk of ~12.5 bm-panels x all 8 bn tiles -> A-panel fetched once into L2.
__global__ void __launch_bounds__(256) gemm1_mfma(
    const unsigned short* __restrict__ Ab, const unsigned short* __restrict__ Bt,
    const float* __restrict__ bias,
    unsigned short* __restrict__ A2, unsigned short* __restrict__ qkvb)
{
    constexpr int K = 512, KIT = K / 64;
    __shared__ unsigned short As[64 * PIT];
    __shared__ unsigned short Bs[128 * PIT];
    int p = blockIdx.x;
    int l = (p & 7) * 100 + (p >> 3);   // 800 = 8 x 100, bijective
    int bm = (l >> 3) * 64, bn = (l & 7) * 128;
    int tid = threadIdx.x, lane = tid & 63, w = tid >> 6;
    int wr = w >> 1, wc = w & 1;
    int nn = lane & 15, qd = lane >> 4;
    int arow = tid >> 2, ac0 = (tid & 3) * 16;      // A: 64 rows x 64 cols, 32B/thread
    int brow = tid >> 1, bc0 = (tid & 1) * 32;      // B: 128 rows x 64 cols, 64B/thread
    const unsigned short* Ag = Ab + (size_t)(bm + arow) * K + ac0;
    const unsigned short* Bg = Bt + (size_t)(bn + brow) * K + bc0;

    short8 pa0 = *(const short8*)Ag, pa1 = *(const short8*)(Ag + 8);
    short8 pb0 = *(const short8*)Bg, pb1 = *(const short8*)(Bg + 8);
    short8 pb2 = *(const short8*)(Bg + 16), pb3 = *(const short8*)(Bg + 24);

    f32x4 acc[2][4];
    #pragma unroll
    for (int i = 0; i < 2; i++)
        #pragma unroll
        for (int j = 0; j < 4; j++) acc[i][j] = (f32x4){0.f, 0.f, 0.f, 0.f};

    for (int it = 0; it < KIT; ++it) {
        __syncthreads();
        *(short8*)&As[arow * PIT + ac0]     = pa0;
        *(short8*)&As[arow * PIT + ac0 + 8] = pa1;
        *(short8*)&Bs[brow * PIT + bc0]      = pb0;
        *(short8*)&Bs[brow * PIT + bc0 + 8]  = pb1;
        *(short8*)&Bs[brow * PIT + bc0 + 16] = pb2;
        *(short8*)&Bs[brow * PIT + bc0 + 24] = pb3;
        __syncthreads();
        if (it + 1 < KIT) {
            int k0 = (it + 1) * 64;
            pa0 = *(const short8*)(Ag + k0); pa1 = *(const short8*)(Ag + k0 + 8);
            pb0 = *(const short8*)(Bg + k0); pb1 = *(const short8*)(Bg + k0 + 8);
            pb2 = *(const short8*)(Bg + k0 + 16); pb3 = *(const short8*)(Bg + k0 + 24);
        }
        #pragma unroll
        for (int kk = 0; kk < 2; kk++) {
            short8 af[2], bf[4];
            #pragma unroll
            for (int i = 0; i < 2; i++)
                af[i] = *(const short8*)&As[(wr * 32 + i * 16 + nn) * PIT + kk * 32 + qd * 8];
            #pragma unroll
            for (int j = 0; j < 4; j++)
                bf[j] = *(const short8*)&Bs[(wc * 64 + j * 16 + nn) * PIT + kk * 32 + qd * 8];
            #pragma unroll
            for (int i = 0; i < 2; i++)
                #pragma unroll
                for (int j = 0; j < 4; j++)
                    acc[i][j] = __builtin_amdgcn_mfma_f32_16x16x32_bf16(af[i], bf[j], acc[i][j], 0, 0, 0);
        }
    }
    bool isU = (bn < 256);   // block-uniform: 128-col tiles align with the u/vqk boundary
    #pragma unroll
    for (int j = 0; j < 4; j++) {
        int col = bn + wc * 64 + j * 16 + nn;
        float bb = bias[col];
        #pragma unroll
        for (int i = 0; i < 2; i++) {
            int rbase = bm + wr * 32 + i * 16 + qd * 4;
            #pragma unroll
            for (int r = 0; r < 4; r++) {
                unsigned short hh = f2bf(silu_f(acc[i][j][r] + bb));
                if (isU) A2[(size_t)(rbase + r) * 1024 + col] = hh;
                else     qkvb[(size_t)(rbase + r) * 768 + col - 256] = hh;
            }
        }
    }
}

// ---------------- GEMM2 (MFMA bf16, 64x128 tile, BK=64): out = x + A2 @ Wo ----------------
// 1D grid, XCD-chunked: l=(p&7)*50+(p>>3); each XCD gets ~12.5 bm-panels x all 4 bn tiles.
__global__ void __launch_bounds__(256) gemm2_mfma(
    const unsigned short* __restrict__ Ab, const unsigned short* __restrict__ Bt,
    const float* __restrict__ x, float* __restrict__ out)
{
    constexpr int K = 1024, KIT = K / 64;
    __shared__ unsigned short As[64 * PIT];
    __shared__ unsigned short Bs[128 * PIT];
    int p = blockIdx.x;
    int l = (p & 7) * 50 + (p >> 3);    // 400 = 8 x 50, bijective
    int bm = (l >> 2) * 64, bn = (l & 3) * 128;
    int tid = threadIdx.x, lane = tid & 63, w = tid >> 6;
    int wr = w >> 1, wc = w & 1;
    int nn = lane & 15, qd = lane >> 4;
    int arow = tid >> 2, ac0 = (tid & 3) * 16;
    int brow = tid >> 1, bc0 = (tid & 1) * 32;
    const unsigned short* Ag = Ab + (size_t)(bm + arow) * K + ac0;
    const unsigned short* Bg = Bt + (size_t)(bn + brow) * K + bc0;

    short8 pa0 = *(const short8*)Ag, pa1 = *(const short8*)(Ag + 8);
    short8 pb0 = *(const short8*)Bg, pb1 = *(const short8*)(Bg + 8);
    short8 pb2 = *(const short8*)(Bg + 16), pb3 = *(const short8*)(Bg + 24);

    f32x4 acc[2][4];
    #pragma unroll
    for (int i = 0; i < 2; i++)
        #pragma unroll
        for (int j = 0; j < 4; j++) acc[i][j] = (f32x4){0.f, 0.f, 0.f, 0.f};

    for (int it = 0; it < KIT; ++it) {
        __syncthreads();
        *(short8*)&As[arow * PIT + ac0]     = pa0;
        *(short8*)&As[arow * PIT + ac0 + 8] = pa1;
        *(short8*)&Bs[brow * PIT + bc0]      = pb0;
        *(short8*)&Bs[brow * PIT + bc0 + 8]  = pb1;
        *(short8*)&Bs[brow * PIT + bc0 + 16] = pb2;
        *(short8*)&Bs[brow * PIT + bc0 + 24] = pb3;
        __syncthreads();
        if (it + 1 < KIT) {
            int k0 = (it + 1) * 64;
            pa0 = *(const short8*)(Ag + k0); pa1 = *(const short8*)(Ag + k0 + 8);
            pb0 = *(const short8*)(Bg + k0); pb1 = *(const short8*)(Bg + k0 + 8);
            pb2 = *(const short8*)(Bg + k0 + 16); pb3 = *(const short8*)(Bg + k0 + 24);
        }
        #pragma unroll
        for (int kk = 0; kk < 2; kk++) {
            short8 af[2], bf[4];
            #pragma unroll
            for (int i = 0; i < 2; i++)
                af[i] = *(const short8*)&As[(wr * 32 + i * 16 + nn) * PIT + kk * 32 + qd * 8];
            #pragma unroll
            for (int j = 0; j < 4; j++)
                bf[j] = *(const short8*)&Bs[(wc * 64 + j * 16 + nn) * PIT + kk * 32 + qd * 8];
            #pragma unroll
            for (int i = 0; i < 2; i++)
                #pragma unroll
                for (int j = 0; j < 4; j++)
                    acc[i][j] = __builtin_amdgcn_mfma_f32_16x16x32_bf16(af[i], bf[j], acc[i][j], 0, 0, 0);
        }
    }
    #pragma unroll
    for (int j = 0; j < 4; j++) {
        int col = bn + wc * 64 + j * 16 + nn;
        #pragma unroll
        for (int i = 0; i < 2; i++) {
            int rbase = bm + wr * 32 + i * 16 + qd * 4;
            #pragma unroll
            for (int r = 0; r < 4; r++) {
                size_t idx = (size_t)(rbase + r) * 512 + col;
                out[idx] = x[idx] + acc[i][j][r];
            }
        }
    }
}

// ---------------- Attention (MFMA bf16, wave-private m-split, no atomics) ----------------
// 1D grid, bh-major id decode: id mod 8 is constant per (b,h) pair -> all tiles of a
// given bh land on the same XCD (2 bh per XCD; K/V working set <= ~832 KB fits 4 MB L2).
// Deep tiles (xt=0 -> n0=1984) get the smallest ids -> dispatched first.
__global__ void __launch_bounds__(256, 2) attn_mfma_kernel(
    const unsigned short* __restrict__ qkvb,
    const int* __restrict__ offsets,
    const int* __restrict__ lengths,
    const int* __restrict__ num_targets,
    float* __restrict__ attn)
{
    int id = blockIdx.x;
    int bh = id & 15;
    int xt = id >> 4;
    int b = bh >> 2, h = bh & 3;
    int len = lengths[b];
    int n0 = (31 - xt) * 64;                // deep tiles dispatched first
    if (n0 >= len) return;
    int m_hi = min(n0 + 63, len - 1);
    int off = offsets[b];
    int max_id = len - num_targets[b];
    int tid = threadIdx.x, lane = tid & 63, w = tid >> 6;
    int nn = lane & 15, qd = lane >> 4;

    __shared__ __align__(16) char smem[69632];
    unsigned short* Vt = (unsigned short*)(smem + w * 9216);  // wave-private 64x72 bf16
    float* Os = (float*)smem;                                 // overlay: 4 x (64x68) f32

    // Q B-frags for all 4 n-groups, alpha=0.125 folded (exact pow2)
    short8 qf[4][2];
    #pragma unroll
    for (int g = 0; g < 4; g++) {
        int row = min(n0 + g * 16 + nn, len - 1);
        const unsigned short* base = qkvb + (size_t)(off + row) * 768 + 256 + h * 64;
        qf[g][0] = scale8_pow2(*(const short8*)(base + qd * 8), 0.125f);
        qf[g][1] = scale8_pow2(*(const short8*)(base + 32 + qd * 8), 0.125f);
    }

    f32x4 o_acc[4][4];   // [t: v-subtile][g: n-group], O^T C-layout
    #pragma unroll
    for (int t = 0; t < 4; t++)
        #pragma unroll
        for (int g = 0; g < 4; g++) o_acc[t][g] = (f32x4){0.f, 0.f, 0.f, 0.f};

    int fast_lim = min(n0, max_id);
    int r0 = (lane & 15) * 4, d0 = (lane >> 4) * 16;   // V staging: 4 rows x 16 dims

    short8 kf[4][2], kn[4][2], vf[4][2];
    int m_first = w * 64;
    if (m_first <= m_hi) {
        #pragma unroll
        for (int s = 0; s < 4; s++) {
            int row = min(m_first + s * 16 + nn, len - 1);
            const unsigned short* kb = qkvb + (size_t)(off + row) * 768 + 512 + h * 64 + qd * 8;
            kf[s][0] = *(const short8*)kb;
            kf[s][1] = *(const short8*)(kb + 32);
        }
        #pragma unroll
        for (int j = 0; j < 4; j++) {
            int row = min(m_first + r0 + j, len - 1);
            const unsigned short* vb = qkvb + (size_t)(off + row) * 768 + h * 64 + d0;
            vf[j][0] = *(const short8*)vb;
            vf[j][1] = *(const short8*)(vb + 8);
        }
    }

    for (int m0 = m_first; m0 <= m_hi; m0 += 256) {
        #pragma unroll
        for (int dd = 0; dd < 16; dd++) {
            int hh = dd >> 3, e = dd & 7;
            short4v pk;
            pk[0] = vf[0][hh][e]; pk[1] = vf[1][hh][e];
            pk[2] = vf[2][hh][e]; pk[3] = vf[3][hh][e];
            *(short4v*)&Vt[(d0 + dd) * PIT + r0] = pk;
        }
        int mnext = m0 + 256;
        if (mnext <= m_hi) {
            #pragma unroll
            for (int j = 0; j < 4; j++) {
                int row = min(mnext + r0 + j, len - 1);
                const unsigned short* vb = qkvb + (size_t)(off + row) * 768 + h * 64 + d0;
                vf[j][0] = *(const short8*)vb;
                vf[j][1] = *(const short8*)(vb + 8);
            }
            #pragma unroll
            for (int s = 0; s < 4; s++) {
                int row = min(mnext + s * 16 + nn, len - 1);
                const unsigned short* kb = qkvb + (size_t)(off + row) * 768 + 512 + h * 64 + qd * 8;
                kn[s][0] = *(const short8*)kb;
                kn[s][1] = *(const short8*)(kb + 32);
            }
        }
        bool fastp = (m0 + 63 < fast_lim);
        #pragma unroll
        for (int s = 0; s < 4; s++) {
            f32x4 st[4];
            __builtin_amdgcn_s_setprio(1);
            #pragma unroll
            for (int g = 0; g < 4; g++) {
                st[g] = (f32x4){0.f, 0.f, 0.f, 0.f};
                st[g] = __builtin_amdgcn_mfma_f32_16x16x32_bf16(kf[s][0], qf[g][0], st[g], 0, 0, 0);
                st[g] = __builtin_amdgcn_mfma_f32_16x16x32_bf16(kf[s][1], qf[g][1], st[g], 0, 0, 0);
            }
            __builtin_amdgcn_s_setprio(0);
            short4v bop[4];
            if (fastp) {
                #pragma unroll
                for (int g = 0; g < 4; g++)
                    #pragma unroll
                    for (int r = 0; r < 4; r++)
                        bop[g][r] = (short)f2bf_fast(silu_f(st[g][r]));
            } else {
                #pragma unroll
                for (int g = 0; g < 4; g++) {
                    int nc_ = n0 + g * 16 + nn;
                    int id_ = min(nc_, max_id);
                    #pragma unroll
                    for (int r = 0; r < 4; r++) {
                        int mcol = m0 + s * 16 + qd * 4 + r;
                        bool ok = (mcol < id_) || (mcol == nc_);
                        bop[g][r] = (short)f2bf_fast(ok ? silu_f(st[g][r]) : 0.f);
                    }
                }
            }
            __builtin_amdgcn_s_setprio(1);
            #pragma unroll
            for (int t = 0; t < 4; t++) {
                short4v aop = *(const short4v*)&Vt[(t * 16 + nn) * PIT + s * 16 + qd * 4];
                #pragma unroll
                for (int g = 0; g < 4; g++)
                    o_acc[t][g] = __builtin_amdgcn_mfma_f32_16x16x16bf16_1k(aop, bop[g], o_acc[t][g], 0, 0, 0);
            }
            __builtin_amdgcn_s_setprio(0);
        }
        if (mnext <= m_hi) {
            #pragma unroll
            for (int s = 0; s < 4; s++) { kf[s][0] = kn[s][0]; kf[s][1] = kn[s][1]; }
        }
    }

    __syncthreads();
    const float invN = 1.f / (float)NSEQ;
    float* Ow = Os + w * 4352;
    #pragma unroll
    for (int t = 0; t < 4; t++)
        #pragma unroll
        for (int g = 0; g < 4; g++) {
            f32x4 v = o_acc[t][g] * invN;
            *(f32x4*)&Ow[(g * 16 + nn) * 68 + t * 16 + qd * 4] = v;
        }
    __syncthreads();
    int rr = tid >> 2, cs = (tid & 3) * 16;
    if (n0 + rr < len) {
        float* dst = attn + (size_t)(off + n0 + rr) * 256 + h * 64 + cs;
        #pragma unroll
        for (int q4 = 0; q4 < 4; q4++) {
            f32x4 v = (f32x4){0.f, 0.f, 0.f, 0.f};
            #pragma unroll
            for (int w2 = 0; w2 < 4; w2++)
                v += *(const f32x4*)&Os[w2 * 4352 + rr * 68 + cs + q4 * 4];
            *(f32x4*)(dst + q4 * 4) = v;
        }
    }
}

extern "C" void kernel_launch(void* const* d_in, const int* in_sizes, int n_in,
                              void* d_out, int out_size, void* d_ws, size_t ws_size,
                              hipStream_t stream)
{
    const float* x          = (const float*)d_in[0];
    const int*   x_lengths  = (const int*)d_in[1];
    const int*   x_offsets  = (const int*)d_in[2];
    // d_in[3] = max_seq_len (2048, hardcoded as NSEQ)
    const int*   num_targets = (const int*)d_in[4];
    const float* uvqk_w     = (const float*)d_in[5];
    const float* uvqk_b     = (const float*)d_in[6];
    const float* in_w       = (const float*)d_in[7];
    const float* in_b       = (const float*)d_in[8];
    const float* out_w      = (const float*)d_in[9];
    const float* out_b      = (const float*)d_in[10];
    const float* Wo         = (const float*)d_in[11];
    float* out = (float*)d_out;

    int L = in_sizes[0] / 512;   // 6400

    char* ws = (char*)d_ws;
    size_t o = 0;
    float* attn = (float*)(ws + o);          o += (size_t)L * 256 * 4;   // fp32 attn
    unsigned short* nxb  = (unsigned short*)(ws + o); o += (size_t)L * 512 * 2;
    unsigned short* A2   = (unsigned short*)(ws + o); o += (size_t)L * 1024 * 2;
    unsigned short* qkvb = (unsigned short*)(ws + o); o += (size_t)L * 768 * 2;
    unsigned short* W1t  = (unsigned short*)(ws + o); o += (size_t)1024 * 512 * 2;
    unsigned short* W2t  = (unsigned short*)(ws + o); o += (size_t)512 * 1024 * 2;

    // 0) weight transposes + input LN, single launch
    prep_kernel<<<dim3(1024 + L / 4), 256, 0, stream>>>(
        uvqk_w, W1t, Wo, W2t, x, in_w, in_b, nxb, A2);

    // 1) uvqk = silu(nx @ W1 + b): u -> A2[:,0:256), v/q/k -> qkvb  (800 blocks, XCD-chunked)
    gemm1_mfma<<<dim3(800), 256, 0, stream>>>(nxb, W1t, uvqk_b, A2, qkvb);

    // 2) attention (1D grid, bh-major XCD-locality swizzle, deep-first)
    attn_mfma_kernel<<<dim3(512), 256, 0, stream>>>(qkvb, x_offsets, x_lengths, num_targets, attn);

    // 3) output LN (wave/row, 4 rows/block) -> bf16 A2[:,768:1024)
    ln256_kernel<<<L / 4, 256, 0, stream>>>(attn, out_w, out_b, A2);

    // 4) out = x + A2 @ Wo  (400 blocks, XCD-chunked)
    gemm2_mfma<<<dim3(400), 256, 0, stream>>>(A2, W2t, x, out);
}

// Round 4
// 158.752 us; speedup vs baseline: 1.1463x; 1.0471x over previous
//
#include <hip/hip_runtime.h>
#include <math.h>

// Problem constants (fixed by setup_inputs):
//   B=4, N=2048, D=512, H=4, A=64, V=64, L=6400
//   qkvb (bf16, L x 768): [0:256)=v, [256:512)=q, [512:768)=k
//   A2   (bf16, L x 1024): [0:256)=u, [256:768)=x, [768:1024)=y
#define NSEQ 2048
#define PIT 72    // LDS pitch (bf16 elems): 144B rows -> 4-bank row shift, b128 reads 2-way (free)

typedef __attribute__((ext_vector_type(8))) short short8;   // 8 bf16 = 4 VGPR
typedef __attribute__((ext_vector_type(4))) short short4v;  // 4 bf16 = 2 VGPR
typedef __attribute__((ext_vector_type(4))) float f32x4;    // MFMA acc

// fast silu: z * rcp(1 + exp(-z)) — 1-ulp rcp instead of correctly-rounded divide
__device__ __forceinline__ float silu_f(float z) {
    return z * __builtin_amdgcn_rcpf(1.f + __expf(-z));
}

__device__ __forceinline__ unsigned short f2bf(float f) {
    unsigned int u = __float_as_uint(f);
    u += 0x7fffu + ((u >> 16) & 1u);   // RNE (finite inputs only)
    return (unsigned short)(u >> 16);
}

__device__ __forceinline__ unsigned short f2bf_fast(float f) {
    return (unsigned short)((__float_as_uint(f) + 0x8000u) >> 16);
}

// exact for power-of-2 scale
__device__ __forceinline__ short8 scale8_pow2(short8 v, float s) {
    short8 r;
    #pragma unroll
    for (int i = 0; i < 8; i++) {
        float f = __uint_as_float(((unsigned int)(unsigned short)v[i]) << 16) * s;
        r[i] = (short)(unsigned short)(__float_as_uint(f) >> 16);
    }
    return r;
}

// ---------------- prep: weight transposes + input LN in ONE launch ----------------
// blocks [0,512):    W1 (512x1024 -> 1024x512 bf16)
// blocks [512,1024): W2 (1024x512 -> 512x1024 bf16)
// blocks [1024, 1024+L/4): ln512, 4 rows/block (wave per row, no barrier)
__global__ void __launch_bounds__(256) prep_kernel(
    const float* __restrict__ W1, unsigned short* __restrict__ W1t,
    const float* __restrict__ W2, unsigned short* __restrict__ W2t,
    const float* __restrict__ x, const float* __restrict__ inw,
    const float* __restrict__ inb,
    unsigned short* __restrict__ nxb, unsigned short* __restrict__ A2)
{
    __shared__ float t[32][33];
    int id = blockIdx.x;
    int tid = threadIdx.x;
    if (id < 1024) {
        const float* W; unsigned short* Wt; int R, C, bx, by;
        if (id < 512) { W = W1; Wt = W1t; R = 512;  C = 1024; bx = id & 31; by = id >> 5; }
        else { int i2 = id - 512; W = W2; Wt = W2t; R = 1024; C = 512; bx = i2 & 15; by = i2 >> 4; }
        int tr = tid >> 5, tc = tid & 31;
        int r0 = by * 32, c0 = bx * 32;
        #pragma unroll
        for (int p = 0; p < 4; p++)
            t[tr + p * 8][tc] = W[(size_t)(r0 + tr + p * 8) * C + c0 + tc];
        __syncthreads();
        #pragma unroll
        for (int p = 0; p < 4; p++)
            Wt[(size_t)(c0 + tr + p * 8) * R + r0 + tc] = f2bf(t[tc][tr + p * 8]);
        return;
    }
    // ---- ln512 path ----
    int lane = tid & 63, wv = tid >> 6;
    int row = (id - 1024) * 4 + wv;
    int c = lane * 8;
    const float* xr = x + (size_t)row * 512 + c;
    float4 v0 = *(const float4*)xr;
    float4 v1 = *(const float4*)(xr + 4);
    float s  = v0.x + v0.y + v0.z + v0.w + v1.x + v1.y + v1.z + v1.w;
    float sq = v0.x * v0.x + v0.y * v0.y + v0.z * v0.z + v0.w * v0.w
             + v1.x * v1.x + v1.y * v1.y + v1.z * v1.z + v1.w * v1.w;
    #pragma unroll
    for (int o = 32; o > 0; o >>= 1) { s += __shfl_xor(s, o); sq += __shfl_xor(sq, o); }
    float mu = s * (1.f / 512.f);
    float var = sq * (1.f / 512.f) - mu * mu;
    float rs = rsqrtf(var + 1e-6f);
    float4 w0 = *(const float4*)(inw + c), w1 = *(const float4*)(inw + c + 4);
    float4 b0 = *(const float4*)(inb + c), b1 = *(const float4*)(inb + c + 4);
    ushort4 hn0, hn1, hx0, hx1;
    hn0.x = f2bf((v0.x - mu) * rs * w0.x + b0.x);
    hn0.y = f2bf((v0.y - mu) * rs * w0.y + b0.y);
    hn0.z = f2bf((v0.z - mu) * rs * w0.z + b0.z);
    hn0.w = f2bf((v0.w - mu) * rs * w0.w + b0.w);
    hn1.x = f2bf((v1.x - mu) * rs * w1.x + b1.x);
    hn1.y = f2bf((v1.y - mu) * rs * w1.y + b1.y);
    hn1.z = f2bf((v1.z - mu) * rs * w1.z + b1.z);
    hn1.w = f2bf((v1.w - mu) * rs * w1.w + b1.w);
    hx0.x = f2bf(v0.x); hx0.y = f2bf(v0.y); hx0.z = f2bf(v0.z); hx0.w = f2bf(v0.w);
    hx1.x = f2bf(v1.x); hx1.y = f2bf(v1.y); hx1.z = f2bf(v1.z); hx1.w = f2bf(v1.w);
    unsigned short* nr = nxb + (size_t)row * 512 + c;
    *(ushort4*)nr = hn0; *(ushort4*)(nr + 4) = hn1;
    unsigned short* ar = A2 + (size_t)row * 1024 + 256 + c;
    *(ushort4*)ar = hx0; *(ushort4*)(ar + 4) = hx1;
}

// ---------------- LN over 256 (output): one wave per row, no LDS/barrier ----------------
__global__ void __launch_bounds__(256) ln256_kernel(
    const float* __restrict__ a, const float* __restrict__ w,
    const float* __restrict__ b, unsigned short* __restrict__ A2)
{
    int tid = threadIdx.x, lane = tid & 63, wv = tid >> 6;
    int row = blockIdx.x * 4 + wv;
    int c = lane * 4;
    float4 v = *(const float4*)(a + (size_t)row * 256 + c);
    float s  = v.x + v.y + v.z + v.w;
    float sq = v.x * v.x + v.y * v.y + v.z * v.z + v.w * v.w;
    #pragma unroll
    for (int o = 32; o > 0; o >>= 1) { s += __shfl_xor(s, o); sq += __shfl_xor(sq, o); }
    float mu = s * (1.f / 256.f);
    float var = sq * (1.f / 256.f) - mu * mu;
    float rs = rsqrtf(var + 1e-6f);
    float4 w4 = *(const float4*)(w + c);
    float4 b4 = *(const float4*)(b + c);
    ushort4 h;
    h.x = f2bf((v.x - mu) * rs * w4.x + b4.x);
    h.y = f2bf((v.y - mu) * rs * w4.y + b4.y);
    h.z = f2bf((v.z - mu) * rs * w4.z + b4.z);
    h.w = f2bf((v.w - mu) * rs * w4.w + b4.w);
    *(ushort4*)(A2 + (size_t)row * 1024 + 768 + c) = h;
}

// ---------------- GEMM1 (MFMA bf16, 64x64 tile, BK=64, reg prefetch) ----------------
// A: nxb (L x 512), B: W1t (1024 x 512, N-major). silu(A@B^T + bias) -> A2 u / qkvb.
// 1600 blocks (6.25/CU; occupancy was the binding constraint at 64x128/800) —
// XCD-chunked bijective: l=(p&7)*200+(p>>3), bm-major within chunk.
__global__ void __launch_bounds__(256) gemm1_mfma(
    const unsigned short* __restrict__ Ab, const unsigned short* __restrict__ Bt,
    const float* __restrict__ bias,
    unsigned short* __restrict__ A2, unsigned short* __restrict__ qkvb)
{
    constexpr int K = 512, KIT = K / 64;
    __shared__ unsigned short As[64 * PIT];
    __shared__ unsigned short Bs[64 * PIT];
    int p = blockIdx.x;
    int l = (p & 7) * 200 + (p >> 3);   // 1600 = 8 x 200, bijective
    int bm = (l >> 4) * 64, bn = (l & 15) * 64;
    int tid = threadIdx.x, lane = tid & 63, w = tid >> 6;
    int wr = w >> 1, wc = w & 1;
    int nn = lane & 15, qd = lane >> 4;
    int arow = tid >> 2, ac0 = (tid & 3) * 16;      // 64 rows x 64 cols, 32B/thread (A and B)
    const unsigned short* Ag = Ab + (size_t)(bm + arow) * K + ac0;
    const unsigned short* Bg = Bt + (size_t)(bn + arow) * K + ac0;

    short8 pa0 = *(const short8*)Ag, pa1 = *(const short8*)(Ag + 8);
    short8 pb0 = *(const short8*)Bg, pb1 = *(const short8*)(Bg + 8);

    f32x4 acc[2][2];
    #pragma unroll
    for (int i = 0; i < 2; i++)
        #pragma unroll
        for (int j = 0; j < 2; j++) acc[i][j] = (f32x4){0.f, 0.f, 0.f, 0.f};

    for (int it = 0; it < KIT; ++it) {
        __syncthreads();
        *(short8*)&As[arow * PIT + ac0]     = pa0;
        *(short8*)&As[arow * PIT + ac0 + 8] = pa1;
        *(short8*)&Bs[arow * PIT + ac0]     = pb0;
        *(short8*)&Bs[arow * PIT + ac0 + 8] = pb1;
        __syncthreads();
        if (it + 1 < KIT) {
            int k0 = (it + 1) * 64;
            pa0 = *(const short8*)(Ag + k0); pa1 = *(const short8*)(Ag + k0 + 8);
            pb0 = *(const short8*)(Bg + k0); pb1 = *(const short8*)(Bg + k0 + 8);
        }
        #pragma unroll
        for (int kk = 0; kk < 2; kk++) {
            short8 af[2], bf[2];
            #pragma unroll
            for (int i = 0; i < 2; i++)
                af[i] = *(const short8*)&As[(wr * 32 + i * 16 + nn) * PIT + kk * 32 + qd * 8];
            #pragma unroll
            for (int j = 0; j < 2; j++)
                bf[j] = *(const short8*)&Bs[(wc * 32 + j * 16 + nn) * PIT + kk * 32 + qd * 8];
            #pragma unroll
            for (int i = 0; i < 2; i++)
                #pragma unroll
                for (int j = 0; j < 2; j++)
                    acc[i][j] = __builtin_amdgcn_mfma_f32_16x16x32_bf16(af[i], bf[j], acc[i][j], 0, 0, 0);
        }
    }
    bool isU = (bn < 256);   // block-uniform: 64-col tiles align with the u/vqk boundary
    #pragma unroll
    for (int j = 0; j < 2; j++) {
        int col = bn + wc * 32 + j * 16 + nn;
        float bb = bias[col];
        #pragma unroll
        for (int i = 0; i < 2; i++) {
            int rbase = bm + wr * 32 + i * 16 + qd * 4;
            #pragma unroll
            for (int r = 0; r < 4; r++) {
                unsigned short hh = f2bf(silu_f(acc[i][j][r] + bb));
                if (isU) A2[(size_t)(rbase + r) * 1024 + col] = hh;
                else     qkvb[(size_t)(rbase + r) * 768 + col - 256] = hh;
            }
        }
    }
}

// ---------------- GEMM2 (MFMA bf16, 64x64 tile, BK=64): out = x + A2 @ Wo ----------------
// 800 blocks (3.1/CU vs 1.56 at 64x128 — occupancy was the binding constraint).
// XCD-chunked bijective: l=(p&7)*100+(p>>3).
__global__ void __launch_bounds__(256) gemm2_mfma(
    const unsigned short* __restrict__ Ab, const unsigned short* __restrict__ Bt,
    const float* __restrict__ x, float* __restrict__ out)
{
    constexpr int K = 1024, KIT = K / 64;
    __shared__ unsigned short As[64 * PIT];
    __shared__ unsigned short Bs[64 * PIT];
    int p = blockIdx.x;
    int l = (p & 7) * 100 + (p >> 3);    // 800 = 8 x 100, bijective
    int bm = (l >> 3) * 64, bn = (l & 7) * 64;
    int tid = threadIdx.x, lane = tid & 63, w = tid >> 6;
    int wr = w >> 1, wc = w & 1;
    int nn = lane & 15, qd = lane >> 4;
    int arow = tid >> 2, ac0 = (tid & 3) * 16;
    const unsigned short* Ag = Ab + (size_t)(bm + arow) * K + ac0;
    const unsigned short* Bg = Bt + (size_t)(bn + arow) * K + ac0;

    short8 pa0 = *(const short8*)Ag, pa1 = *(const short8*)(Ag + 8);
    short8 pb0 = *(const short8*)Bg, pb1 = *(const short8*)(Bg + 8);

    f32x4 acc[2][2];
    #pragma unroll
    for (int i = 0; i < 2; i++)
        #pragma unroll
        for (int j = 0; j < 2; j++) acc[i][j] = (f32x4){0.f, 0.f, 0.f, 0.f};

    for (int it = 0; it < KIT; ++it) {
        __syncthreads();
        *(short8*)&As[arow * PIT + ac0]     = pa0;
        *(short8*)&As[arow * PIT + ac0 + 8] = pa1;
        *(short8*)&Bs[arow * PIT + ac0]     = pb0;
        *(short8*)&Bs[arow * PIT + ac0 + 8] = pb1;
        __syncthreads();
        if (it + 1 < KIT) {
            int k0 = (it + 1) * 64;
            pa0 = *(const short8*)(Ag + k0); pa1 = *(const short8*)(Ag + k0 + 8);
            pb0 = *(const short8*)(Bg + k0); pb1 = *(const short8*)(Bg + k0 + 8);
        }
        #pragma unroll
        for (int kk = 0; kk < 2; kk++) {
            short8 af[2], bf[2];
            #pragma unroll
            for (int i = 0; i < 2; i++)
                af[i] = *(const short8*)&As[(wr * 32 + i * 16 + nn) * PIT + kk * 32 + qd * 8];
            #pragma unroll
            for (int j = 0; j < 2; j++)
                bf[j] = *(const short8*)&Bs[(wc * 32 + j * 16 + nn) * PIT + kk * 32 + qd * 8];
            #pragma unroll
            for (int i = 0; i < 2; i++)
                #pragma unroll
                for (int j = 0; j < 2; j++)
                    acc[i][j] = __builtin_amdgcn_mfma_f32_16x16x32_bf16(af[i], bf[j], acc[i][j], 0, 0, 0);
        }
    }
    #pragma unroll
    for (int j = 0; j < 2; j++) {
        int col = bn + wc * 32 + j * 16 + nn;
        #pragma unroll
        for (int i = 0; i < 2; i++) {
            int rbase = bm + wr * 32 + i * 16 + qd * 4;
            #pragma unroll
            for (int r = 0; r < 4; r++) {
                size_t idx = (size_t)(rbase + r) * 512 + col;
                out[idx] = x[idx] + acc[i][j][r];
            }
        }
    }
}

// ---------------- Attention (MFMA bf16, wave-private m-split, no atomics) ----------------
// 1D grid, bh-major id decode: id mod 8 is constant per (b,h) pair -> all tiles of a
// given bh land on the same XCD (2 bh per XCD; K/V working set <= ~832 KB fits 4 MB L2).
// Deep tiles (xt=0 -> n0=1984) get the smallest ids -> dispatched first.
__global__ void __launch_bounds__(256, 2) attn_mfma_kernel(
    const unsigned short* __restrict__ qkvb,
    const int* __restrict__ offsets,
    const int* __restrict__ lengths,
    const int* __restrict__ num_targets,
    float* __restrict__ attn)
{
    int id = blockIdx.x;
    int bh = id & 15;
    int xt = id >> 4;
    int b = bh >> 2, h = bh & 3;
    int len = lengths[b];
    int n0 = (31 - xt) * 64;                // deep tiles dispatched first
    if (n0 >= len) return;
    int m_hi = min(n0 + 63, len - 1);
    int off = offsets[b];
    int max_id = len - num_targets[b];
    int tid = threadIdx.x, lane = tid & 63, w = tid >> 6;
    int nn = lane & 15, qd = lane >> 4;

    __shared__ __align__(16) char smem[69632];
    unsigned short* Vt = (unsigned short*)(smem + w * 9216);  // wave-private 64x72 bf16
    float* Os = (float*)smem;                                 // overlay: 4 x (64x68) f32

    // Q B-frags for all 4 n-groups, alpha=0.125 folded (exact pow2)
    short8 qf[4][2];
    #pragma unroll
    for (int g = 0; g < 4; g++) {
        int row = min(n0 + g * 16 + nn, len - 1);
        const unsigned short* base = qkvb + (size_t)(off + row) * 768 + 256 + h * 64;
        qf[g][0] = scale8_pow2(*(const short8*)(base + qd * 8), 0.125f);
        qf[g][1] = scale8_pow2(*(const short8*)(base + 32 + qd * 8), 0.125f);
    }

    f32x4 o_acc[4][4];   // [t: v-subtile][g: n-group], O^T C-layout
    #pragma unroll
    for (int t = 0; t < 4; t++)
        #pragma unroll
        for (int g = 0; g < 4; g++) o_acc[t][g] = (f32x4){0.f, 0.f, 0.f, 0.f};

    int fast_lim = min(n0, max_id);
    int r0 = (lane & 15) * 4, d0 = (lane >> 4) * 16;   // V staging: 4 rows x 16 dims

    short8 kf[4][2], kn[4][2], vf[4][2];
    int m_first = w * 64;
    if (m_first <= m_hi) {
        #pragma unroll
        for (int s = 0; s < 4; s++) {
            int row = min(m_first + s * 16 + nn, len - 1);
            const unsigned short* kb = qkvb + (size_t)(off + row) * 768 + 512 + h * 64 + qd * 8;
            kf[s][0] = *(const short8*)kb;
            kf[s][1] = *(const short8*)(kb + 32);
        }
        #pragma unroll
        for (int j = 0; j < 4; j++) {
            int row = min(m_first + r0 + j, len - 1);
            const unsigned short* vb = qkvb + (size_t)(off + row) * 768 + h * 64 + d0;
            vf[j][0] = *(const short8*)vb;
            vf[j][1] = *(const short8*)(vb + 8);
        }
    }

    for (int m0 = m_first; m0 <= m_hi; m0 += 256) {
        #pragma unroll
        for (int dd = 0; dd < 16; dd++) {
            int hh = dd >> 3, e = dd & 7;
            short4v pk;
            pk[0] = vf[0][hh][e]; pk[1] = vf[1][hh][e];
            pk[2] = vf[2][hh][e]; pk[3] = vf[3][hh][e];
            *(short4v*)&Vt[(d0 + dd) * PIT + r0] = pk;
        }
        int mnext = m0 + 256;
        if (mnext <= m_hi) {
            #pragma unroll
            for (int j = 0; j < 4; j++) {
                int row = min(mnext + r0 + j, len - 1);
                const unsigned short* vb = qkvb + (size_t)(off + row) * 768 + h * 64 + d0;
                vf[j][0] = *(const short8*)vb;
                vf[j][1] = *(const short8*)(vb + 8);
            }
            #pragma unroll
            for (int s = 0; s < 4; s++) {
                int row = min(mnext + s * 16 + nn, len - 1);
                const unsigned short* kb = qkvb + (size_t)(off + row) * 768 + 512 + h * 64 + qd * 8;
                kn[s][0] = *(const short8*)kb;
                kn[s][1] = *(const short8*)(kb + 32);
            }
        }
        bool fastp = (m0 + 63 < fast_lim);
        #pragma unroll
        for (int s = 0; s < 4; s++) {
            f32x4 st[4];
            __builtin_amdgcn_s_setprio(1);
            #pragma unroll
            for (int g = 0; g < 4; g++) {
                st[g] = (f32x4){0.f, 0.f, 0.f, 0.f};
                st[g] = __builtin_amdgcn_mfma_f32_16x16x32_bf16(kf[s][0], qf[g][0], st[g], 0, 0, 0);
                st[g] = __builtin_amdgcn_mfma_f32_16x16x32_bf16(kf[s][1], qf[g][1], st[g], 0, 0, 0);
            }
            __builtin_amdgcn_s_setprio(0);
            short4v bop[4];
            if (fastp) {
                #pragma unroll
                for (int g = 0; g < 4; g++)
                    #pragma unroll
                    for (int r = 0; r < 4; r++)
                        bop[g][r] = (short)f2bf_fast(silu_f(st[g][r]));
            } else {
                #pragma unroll
                for (int g = 0; g < 4; g++) {
                    int nc_ = n0 + g * 16 + nn;
                    int id_ = min(nc_, max_id);
                    #pragma unroll
                    for (int r = 0; r < 4; r++) {
                        int mcol = m0 + s * 16 + qd * 4 + r;
                        bool ok = (mcol < id_) || (mcol == nc_);
                        bop[g][r] = (short)f2bf_fast(ok ? silu_f(st[g][r]) : 0.f);
                    }
                }
            }
            __builtin_amdgcn_s_setprio(1);
            #pragma unroll
            for (int t = 0; t < 4; t++) {
                short4v aop = *(const short4v*)&Vt[(t * 16 + nn) * PIT + s * 16 + qd * 4];
                #pragma unroll
                for (int g = 0; g < 4; g++)
                    o_acc[t][g] = __builtin_amdgcn_mfma_f32_16x16x16bf16_1k(aop, bop[g], o_acc[t][g], 0, 0, 0);
            }
            __builtin_amdgcn_s_setprio(0);
        }
        if (mnext <= m_hi) {
            #pragma unroll
            for (int s = 0; s < 4; s++) { kf[s][0] = kn[s][0]; kf[s][1] = kn[s][1]; }
        }
    }

    __syncthreads();
    const float invN = 1.f / (float)NSEQ;
    float* Ow = Os + w * 4352;
    #pragma unroll
    for (int t = 0; t < 4; t++)
        #pragma unroll
        for (int g = 0; g < 4; g++) {
            f32x4 v = o_acc[t][g] * invN;
            *(f32x4*)&Ow[(g * 16 + nn) * 68 + t * 16 + qd * 4] = v;
        }
    __syncthreads();
    int rr = tid >> 2, cs = (tid & 3) * 16;
    if (n0 + rr < len) {
        float* dst = attn + (size_t)(off + n0 + rr) * 256 + h * 64 + cs;
        #pragma unroll
        for (int q4 = 0; q4 < 4; q4++) {
            f32x4 v = (f32x4){0.f, 0.f, 0.f, 0.f};
            #pragma unroll
            for (int w2 = 0; w2 < 4; w2++)
                v += *(const f32x4*)&Os[w2 * 4352 + rr * 68 + cs + q4 * 4];
            *(f32x4*)(dst + q4 * 4) = v;
        }
    }
}

extern "C" void kernel_launch(void* const* d_in, const int* in_sizes, int n_in,
                              void* d_out, int out_size, void* d_ws, size_t ws_size,
                              hipStream_t stream)
{
    const float* x          = (const float*)d_in[0];
    const int*   x_lengths  = (const int*)d_in[1];
    const int*   x_offsets  = (const int*)d_in[2];
    // d_in[3] = max_seq_len (2048, hardcoded as NSEQ)
    const int*   num_targets = (const int*)d_in[4];
    const float* uvqk_w     = (const float*)d_in[5];
    const float* uvqk_b     = (const float*)d_in[6];
    const float* in_w       = (const float*)d_in[7];
    const float* in_b       = (const float*)d_in[8];
    const float* out_w      = (const float*)d_in[9];
    const float* out_b      = (const float*)d_in[10];
    const float* Wo         = (const float*)d_in[11];
    float* out = (float*)d_out;

    int L = in_sizes[0] / 512;   // 6400

    char* ws = (char*)d_ws;
    size_t o = 0;
    float* attn = (float*)(ws + o);          o += (size_t)L * 256 * 4;   // fp32 attn
    unsigned short* nxb  = (unsigned short*)(ws + o); o += (size_t)L * 512 * 2;
    unsigned short* A2   = (unsigned short*)(ws + o); o += (size_t)L * 1024 * 2;
    unsigned short* qkvb = (unsigned short*)(ws + o); o += (size_t)L * 768 * 2;
    unsigned short* W1t  = (unsigned short*)(ws + o); o += (size_t)1024 * 512 * 2;
    unsigned short* W2t  = (unsigned short*)(ws + o); o += (size_t)512 * 1024 * 2;

    // 0) weight transposes + input LN, single launch
    prep_kernel<<<dim3(1024 + L / 4), 256, 0, stream>>>(
        uvqk_w, W1t, Wo, W2t, x, in_w, in_b, nxb, A2);

    // 1) uvqk = silu(nx @ W1 + b): u -> A2[:,0:256), v/q/k -> qkvb  (1600 blocks, XCD-chunked)
    gemm1_mfma<<<dim3(1600), 256, 0, stream>>>(nxb, W1t, uvqk_b, A2, qkvb);

    // 2) attention (1D grid, bh-major XCD-locality swizzle, deep-first)
    attn_mfma_kernel<<<dim3(512), 256, 0, stream>>>(qkvb, x_offsets, x_lengths, num_targets, attn);

    // 3) output LN (wave/row, 4 rows/block) -> bf16 A2[:,768:1024)
    ln256_kernel<<<L / 4, 256, 0, stream>>>(attn, out_w, out_b, A2);

    // 4) out = x + A2 @ Wo  (800 blocks, XCD-chunked)
    gemm2_mfma<<<dim3(800), 256, 0, stream>>>(A2, W2t, x, out);
}